// Round 3
// baseline (4644.005 us; speedup 1.0000x reference)
//
#include <hip/hip_runtime.h>
#include <hip/hip_bf16.h>

#define K_CODES 8192
#define DIM     512
#define N_VEC   32768
#define MARGIN  0.35f   // flag threshold on g = x.e - e2/2 ; ~10 sigma of bf16 error

typedef __attribute__((ext_vector_type(8))) short   short8;   // bf16x8 MFMA operand
typedef __attribute__((ext_vector_type(8))) unsigned short ushort8;
typedef __attribute__((ext_vector_type(4))) float   float4x;  // MFMA C/D frag

// async global->LDS, 16 B/lane. LDS dest = wave-uniform base + lane*16.
__device__ inline void gl_lds16(const void* g, void* l) {
    __builtin_amdgcn_global_load_lds(
        (const __attribute__((address_space(1))) unsigned int*)g,
        (__attribute__((address_space(3))) unsigned int*)l, 16, 0, 0);
}

// fp32 -> bf16 bits, round-to-nearest-even
__device__ inline unsigned short f2bf(float f) {
    unsigned int u = __float_as_uint(f);
    return (unsigned short)((u + 0x7FFFu + ((u >> 16) & 1u)) >> 16);
}

// ---------------------------------------------------------------------------
// Kernel 1: prep. rows [0,N_VEC) from z -> zh + x2 ; rows [N_VEC,+K) from cb
// -> ch + hne2 = -0.5*||e||^2.  One wave per row.
// ---------------------------------------------------------------------------
__global__ __launch_bounds__(256) void vq_prep(
    const float* __restrict__ z, const float* __restrict__ cb,
    float* __restrict__ x2, float* __restrict__ hne2,
    unsigned short* __restrict__ zh, unsigned short* __restrict__ ch) {
    int wave = threadIdx.x >> 6;
    int lane = threadIdx.x & 63;
    int row  = blockIdx.x * 4 + wave;
    bool isZ = row < N_VEC;
    int lr = isZ ? row : row - N_VEC;
    const float* src = isZ ? z + (size_t)row * DIM : cb + (size_t)lr * DIM;

    const float4* s4 = (const float4*)src;
    float4 v0 = s4[lane * 2];
    float4 v1 = s4[lane * 2 + 1];
    float f[8] = {v0.x, v0.y, v0.z, v0.w, v1.x, v1.y, v1.z, v1.w};

    float s = 0.0f;
    ushort8 h8;
#pragma unroll
    for (int i = 0; i < 8; ++i) { s += f[i] * f[i]; h8[i] = f2bf(f[i]); }
    ((ushort8*)(isZ ? zh : ch))[(size_t)lr * 64 + lane] = h8;

#pragma unroll
    for (int off = 32; off >= 1; off >>= 1) s += __shfl_xor(s, off, 64);
    if (lane == 0) {
        if (isZ) x2[lr] = s;
        else     hne2[lr] = -0.5f * s;
    }
}

// ---------------------------------------------------------------------------
// Kernel 2: bf16 MFMA GEMM + fused top-2 argmax of g = x.e - e2/2.
// Block = 128 rows x 4096 codes (half=blockIdx.y), 16 tiles of 256 codes.
// 4 waves in 2x2 (wM x wN); per-wave 64x128 tile = 4 M-frags x 8 N-frags.
// Partials written RACE-FREE to slot = half*2 + wN (4 slots per row).
// ---------------------------------------------------------------------------
__global__ __launch_bounds__(256, 2) void vq_gemm(
    const unsigned short* __restrict__ zh, const unsigned short* __restrict__ ch,
    const float* __restrict__ hne2,
    float* __restrict__ pG, int* __restrict__ pN, float* __restrict__ pG2) {
    __shared__ short8 AsC[1024];   // 128 rows x 8 octet-cells, XOR-swizzled (16 KB)
    __shared__ short8 BsC[2048];   // 256 codes x 8 octet-cells, XOR-swizzled (32 KB)

    const int tid  = threadIdx.x;
    const int w    = tid >> 6;
    const int lane = tid & 63;
    const int wM   = w & 1;
    const int wN   = w >> 1;
    const int rowBase   = blockIdx.x * 128;
    const int half      = blockIdx.y;
    const int codeBase0 = half * 4096;

    const int low3 = lane & 7, m15 = lane & 15, hi4 = lane >> 4;

    unsigned aOff[4];
#pragma unroll
    for (int i = 0; i < 4; ++i) {
        int cell = (w * 4 + i) * 64 + lane;
        int r = cell >> 3, qs = cell & 7, q = qs ^ (r & 7);
        aOff[i] = ((unsigned)(rowBase + r) * DIM + q * 8) * 2;
    }
    unsigned bOff[8];
#pragma unroll
    for (int i = 0; i < 8; ++i) {
        int cell = (w * 8 + i) * 64 + lane;
        int c = cell >> 3, qs = cell & 7, q = qs ^ (c & 7);
        bOff[i] = ((unsigned)c * DIM + q * 8) * 2;   // relative to code-tile base
    }

    int rIdx[4], cIdx[8];
#pragma unroll
    for (int mf = 0; mf < 4; ++mf) rIdx[mf] = (wM * 64 + mf * 16 + m15) * 8;
#pragma unroll
    for (int nf = 0; nf < 8; ++nf) cIdx[nf] = (wN * 128 + nf * 16 + m15) * 8;

    float g1[4][4], g2[4][4];
    int   n1[4][4];
#pragma unroll
    for (int mf = 0; mf < 4; ++mf)
#pragma unroll
        for (int rg = 0; rg < 4; ++rg) {
            g1[mf][rg] = -3.4e38f; g2[mf][rg] = -3.4e38f; n1[mf][rg] = 0;
        }

    const char* pA = (const char*)zh;
    for (int ct = 0; ct < 16; ++ct) {
        const int codeBase = codeBase0 + ct * 256;
        const char* pB = (const char*)ch + (size_t)codeBase * (DIM * 2);
        float4x acc[4][8];
#pragma unroll
        for (int mf = 0; mf < 4; ++mf)
#pragma unroll
            for (int nf = 0; nf < 8; ++nf) acc[mf][nf] = (float4x){0.f, 0.f, 0.f, 0.f};

        for (int dc = 0; dc < DIM; dc += 64) {
            const int dc2 = dc * 2;
            __syncthreads();
#pragma unroll
            for (int i = 0; i < 4; ++i)
                gl_lds16(pA + aOff[i] + dc2, &AsC[(w * 4 + i) * 64]);
#pragma unroll
            for (int i = 0; i < 8; ++i)
                gl_lds16(pB + bOff[i] + dc2, &BsC[(w * 8 + i) * 64]);
            __syncthreads();

#pragma unroll
            for (int ks = 0; ks < 2; ++ks) {
                const int qx = (ks * 4 + hi4) ^ low3;
                short8 a[4];
#pragma unroll
                for (int mf = 0; mf < 4; ++mf) a[mf] = AsC[rIdx[mf] + qx];
#pragma unroll
                for (int nf = 0; nf < 8; ++nf) {
                    short8 b = BsC[cIdx[nf] + qx];
#pragma unroll
                    for (int mf = 0; mf < 4; ++mf)
                        acc[mf][nf] = __builtin_amdgcn_mfma_f32_16x16x32_bf16(
                            a[mf], b, acc[mf][nf], 0, 0, 0);
                }
            }
        }

        // epilogue: running top-2 of g (ties -> g2=g1 -> gap 0 -> rescued)
#pragma unroll
        for (int nf = 0; nf < 8; ++nf) {
            int nb = codeBase + wN * 128 + nf * 16 + m15;
            float hv = hne2[nb];
#pragma unroll
            for (int mf = 0; mf < 4; ++mf) {
#pragma unroll
                for (int rg = 0; rg < 4; ++rg) {
                    float g = acc[mf][nf][rg] + hv;
                    if (g > g1[mf][rg]) {
                        g2[mf][rg] = g1[mf][rg];
                        g1[mf][rg] = g; n1[mf][rg] = nb;
                    } else {
                        g2[mf][rg] = fmaxf(g2[mf][rg], g);
                    }
                }
            }
        }
    }

    // cross-lane top-2 merge over the 16 lanes sharing each row
#pragma unroll
    for (int mf = 0; mf < 4; ++mf)
#pragma unroll
        for (int rg = 0; rg < 4; ++rg) {
            float a1 = g1[mf][rg], a2 = g2[mf][rg];
            int   an = n1[mf][rg];
#pragma unroll
            for (int off = 1; off <= 8; off <<= 1) {
                float b1 = __shfl_xor(a1, off, 64);
                int   bn = __shfl_xor(an, off, 64);
                float b2 = __shfl_xor(a2, off, 64);
                if (b1 > a1 || (b1 == a1 && bn < an)) {
                    a2 = fmaxf(a1, b2); a1 = b1; an = bn;
                } else {
                    a2 = fmaxf(a2, b1);
                }
            }
            if (m15 == 0) {
                int row  = rowBase + wM * 64 + mf * 16 + hi4 * 4 + rg;
                int slot = half * 2 + wN;          // unique per (block.y, wave-col)
                pG [slot * N_VEC + row] = a1;
                pN [slot * N_VEC + row] = an;
                pG2[slot * N_VEC + row] = a2;
            }
        }
}

// ---------------------------------------------------------------------------
// Kernel 3: merge 4 partial slots per row, flag near-ties for rescue.
// Writes merged g1 back into pG slot 0 (own row only -> safe).
// ---------------------------------------------------------------------------
__global__ __launch_bounds__(256) void vq_scan(
    float* __restrict__ pG, const int* __restrict__ pN,
    const float* __restrict__ pG2,
    int* __restrict__ provIdx, int* __restrict__ flags,
    unsigned long long* __restrict__ keys,
    int* __restrict__ rescueRows, int* __restrict__ rescueCnt) {
    int r = blockIdx.x * 256 + threadIdx.x;
    float g1 = pG[r], g2 = pG2[r];
    int   n1 = pN[r];
#pragma unroll
    for (int s = 1; s < 4; ++s) {
        float a1 = pG [s * N_VEC + r];
        int   an = pN [s * N_VEC + r];
        float a2 = pG2[s * N_VEC + r];
        if (a1 > g1 || (a1 == g1 && an < n1)) {
            g2 = fmaxf(g1, a2); g1 = a1; n1 = an;
        } else {
            g2 = fmaxf(g2, a1);
        }
    }
    provIdx[r] = n1;
    pG[r] = g1;                       // merged best (for loss)
    int fl = (g1 - g2 < MARGIN) ? 1 : 0;
    flags[r] = fl;
    if (fl) {
        keys[r] = ~0ull;
        int p = atomicAdd(rescueCnt, 1);
        rescueRows[p] = r;
    }
}

// ---------------------------------------------------------------------------
// Kernel 4: exact fp32 rescue, code-major. Block = 16 codes staged in LDS,
// streams all flagged rows (4 at a time). Resolution via atomicMin on
// packed (distKey fp32 bits | code) -> exact min + lowest-index tiebreak.
// distKey = e2/2 - x.e  (provably > 0 for this data: e2min/2 ~193 > Smax ~141)
// ---------------------------------------------------------------------------
__global__ __launch_bounds__(256) void vq_rescue(
    const float* __restrict__ cb, const float* __restrict__ z,
    const float* __restrict__ hne2,
    const int* __restrict__ rescueRows, const int* __restrict__ rescueCnt,
    unsigned long long* __restrict__ keys) {
    __shared__ float cbs[16][516];    // +4 pad: spreads c-groups across banks
    __shared__ float zs[4][512];
    __shared__ float e2h[16];

    const int tid = threadIdx.x;
    const int codeBase = blockIdx.x * 16;

    {   // stage 16 codes x 512 dims (each thread: code tid>>4, dims (tid&15)*32..)
        int c = tid >> 4, l16 = tid & 15;
        const float4* src = (const float4*)(cb + (size_t)(codeBase + c) * DIM + l16 * 32);
#pragma unroll
        for (int q = 0; q < 8; ++q) {
            float4 v = src[q];
            *(float4*)&cbs[c][l16 * 32 + q * 4] = v;
        }
        if (tid < 16) e2h[tid] = -hne2[codeBase + tid];   // = +e2/2
    }

    const int cnt = *rescueCnt;
    const int c = tid >> 4, h = (tid >> 2) & 3, ri = tid & 3;

    for (int r0 = 0; r0 < cnt; r0 += 4) {
        __syncthreads();
        {   // stage up to 4 flagged rows
            int rr = tid >> 6, part = tid & 63;
            int rowIdx = rescueRows[(r0 + rr < cnt) ? (r0 + rr) : r0];
            const float4* zsrc = (const float4*)(z + (size_t)rowIdx * DIM);
            *(float4*)&zs[rr][part * 8]     = zsrc[part * 2];
            *(float4*)&zs[rr][part * 8 + 4] = zsrc[part * 2 + 1];
        }
        __syncthreads();
        if (r0 + ri < cnt) {
            float s = 0.f;
            const float* zp = &zs[ri][h * 128];
            const float* cp = &cbs[c][h * 128];
#pragma unroll
            for (int d = 0; d < 128; d += 4) {
                float4 a = *(const float4*)(zp + d);
                float4 b = *(const float4*)(cp + d);
                s += a.x * b.x + a.y * b.y + a.z * b.z + a.w * b.w;
            }
            s += __shfl_xor(s, 4, 64);   // sum over h (bits 2-3 of tid)
            s += __shfl_xor(s, 8, 64);
            if (h == 0) {
                float kv = e2h[c] - s;    // = e2/2 - x.e  (> 0)
                unsigned long long key =
                    ((unsigned long long)__float_as_uint(kv) << 32) |
                    (unsigned long long)(unsigned)(codeBase + c);
                atomicMin(&keys[rescueRows[r0 + ri]], key);
            }
        }
    }
}

// ---------------------------------------------------------------------------
// Kernel 5: final per-row results: index, counts, loss partial, z_q gather.
// ---------------------------------------------------------------------------
__global__ __launch_bounds__(256) void vq_final(
    const float* __restrict__ gBest, const int* __restrict__ provIdx,
    const int* __restrict__ flags, const unsigned long long* __restrict__ keys,
    const float* __restrict__ x2, const float* __restrict__ cb,
    float* __restrict__ zq, float* __restrict__ idxf,
    float* __restrict__ counts, float* __restrict__ lossAcc) {
    __shared__ int   sIdx[256];
    __shared__ float wsum[4];
    const int tid = threadIdx.x;
    const int r   = blockIdx.x * 256 + tid;

    int n; float dist;
    if (flags[r]) {
        unsigned long long k = keys[r];
        n = (int)(unsigned)(k & 0xffffffffu);
        float kv = __uint_as_float((unsigned)(k >> 32));
        dist = x2[r] + 2.0f * kv;          // x2 + e2 - 2 x.e
    } else {
        n = provIdx[r];
        dist = x2[r] - 2.0f * gBest[r];
    }
    sIdx[tid] = n;
    idxf[r]   = (float)n;
    atomicAdd(&counts[n], 1.0f);

    float ls = dist;
#pragma unroll
    for (int off = 32; off >= 1; off >>= 1) ls += __shfl_xor(ls, off, 64);
    if ((tid & 63) == 0) wsum[tid >> 6] = ls;
    __syncthreads();
    if (tid == 0) atomicAdd(lossAcc, wsum[0] + wsum[1] + wsum[2] + wsum[3]);

    const float4* cb4 = (const float4*)cb;
    float4* zq4 = (float4*)(zq + (size_t)blockIdx.x * 256 * DIM);
    for (int t = tid; t < 256 * (DIM / 4); t += 256) {
        int row = t >> 7, f4 = t & 127;
        zq4[(size_t)row * 128 + f4] = cb4[(size_t)sIdx[row] * 128 + f4];
    }
}

// ---------------------------------------------------------------------------
// Kernel 6: finalize scalars
// ---------------------------------------------------------------------------
__global__ __launch_bounds__(256) void vq_finalize(const float* __restrict__ counts,
                                                   const float* __restrict__ lossAcc,
                                                   float* __restrict__ out_loss,
                                                   float* __restrict__ out_perp) {
    __shared__ float wsum[4];
    int tid = threadIdx.x;
    float s = 0.0f;
    for (int i = tid; i < K_CODES; i += 256) {
        float p = counts[i] * (1.0f / (float)N_VEC);
        s += p * logf(p + 1e-10f);
    }
#pragma unroll
    for (int off = 32; off >= 1; off >>= 1) s += __shfl_xor(s, off, 64);
    if ((tid & 63) == 0) wsum[tid >> 6] = s;
    __syncthreads();
    if (tid == 0) {
        *out_perp = expf(-(wsum[0] + wsum[1] + wsum[2] + wsum[3]));
        *out_loss = 1.25f * lossAcc[0] / (float)(N_VEC * DIM);
    }
}

// ---------------------------------------------------------------------------
// ws layout (bytes), total ~44.6 MB:
//   x2 @0 131072 | hne2 @131072 32768 | counts @163840 32768 | lossAcc @196608 4
//   rescueCnt @196612 4 | provIdx @262144 131072 | flags @393216 131072
//   keys @524288 262144 | rescueRows @786432 131072
//   pG @1048576 524288 | pN @1572864 524288 | pG2 @2097152 524288
//   zh @2621440 33554432 | ch @36175872 8388608
// ---------------------------------------------------------------------------
extern "C" void kernel_launch(void* const* d_in, const int* in_sizes, int n_in,
                              void* d_out, int out_size, void* d_ws, size_t ws_size,
                              hipStream_t stream) {
    (void)in_sizes; (void)n_in; (void)out_size; (void)ws_size;
    const float* z  = (const float*)d_in[0];
    const float* cb = (const float*)d_in[1];

    char* ws = (char*)d_ws;
    float* x2        = (float*)(ws + 0);
    float* hne2      = (float*)(ws + 131072);
    float* counts    = (float*)(ws + 163840);
    float* lossAcc   = (float*)(ws + 196608);
    int*   rescueCnt = (int*)  (ws + 196612);
    int*   provIdx   = (int*)  (ws + 262144);
    int*   flags     = (int*)  (ws + 393216);
    unsigned long long* keys = (unsigned long long*)(ws + 524288);
    int*   rescueRows = (int*) (ws + 786432);
    float* pG        = (float*)(ws + 1048576);
    int*   pN        = (int*)  (ws + 1572864);
    float* pG2       = (float*)(ws + 2097152);
    unsigned short* zh = (unsigned short*)(ws + 2621440);
    unsigned short* ch = (unsigned short*)(ws + 36175872);

    float* out      = (float*)d_out;
    float* zq       = out;
    float* out_loss = out + 16777216;
    float* idxf     = out + 16777217;
    float* out_perp = out + 16777217 + 32768;

    // zero counts + lossAcc + rescueCnt (contiguous)
    hipMemsetAsync(counts, 0, 32768 + 8, stream);
    vq_prep<<<(N_VEC + K_CODES) / 4, 256, 0, stream>>>(z, cb, x2, hne2, zh, ch);
    dim3 grid(N_VEC / 128, 2);
    vq_gemm<<<grid, 256, 0, stream>>>(zh, ch, hne2, pG, pN, pG2);
    vq_scan<<<N_VEC / 256, 256, 0, stream>>>(pG, pN, pG2, provIdx, flags, keys,
                                             rescueRows, rescueCnt);
    vq_rescue<<<K_CODES / 16, 256, 0, stream>>>(cb, z, hne2, rescueRows, rescueCnt, keys);
    vq_final<<<N_VEC / 256, 256, 0, stream>>>(pG, provIdx, flags, keys, x2, cb,
                                              zq, idxf, counts, lossAcc);
    vq_finalize<<<1, 256, 0, stream>>>(counts, lossAcc, out_loss, out_perp);
}

// Round 4
// 660.419 us; speedup vs baseline: 7.0319x; 7.0319x over previous
//
#include <hip/hip_runtime.h>
#include <hip/hip_bf16.h>

#define K_CODES 8192
#define DIM     512
#define N_VEC   32768
#define MARGIN  0.35f   // flag threshold on g = x.e - e2/2 ; ~10 sigma of bf16 error

typedef __attribute__((ext_vector_type(8))) short   short8;   // bf16x8 MFMA operand
typedef __attribute__((ext_vector_type(8))) unsigned short ushort8;
typedef __attribute__((ext_vector_type(4))) float   float4x;  // MFMA C/D frag

// async global->LDS, 16 B/lane. LDS dest = wave-uniform base + lane*16.
__device__ inline void gl_lds16(const void* g, void* l) {
    __builtin_amdgcn_global_load_lds(
        (const __attribute__((address_space(1))) unsigned int*)g,
        (__attribute__((address_space(3))) unsigned int*)l, 16, 0, 0);
}

// fp32 -> bf16 bits, round-to-nearest-even
__device__ inline unsigned short f2bf(float f) {
    unsigned int u = __float_as_uint(f);
    return (unsigned short)((u + 0x7FFFu + ((u >> 16) & 1u)) >> 16);
}

// ---------------------------------------------------------------------------
// Kernel 1: prep. rows [0,N_VEC) from z -> zh + x2 ; rows [N_VEC,+K) from cb
// -> ch + hne2 = -0.5*||e||^2.  One wave per row.
// ---------------------------------------------------------------------------
__global__ __launch_bounds__(256) void vq_prep(
    const float* __restrict__ z, const float* __restrict__ cb,
    float* __restrict__ x2, float* __restrict__ hne2,
    unsigned short* __restrict__ zh, unsigned short* __restrict__ ch) {
    int wave = threadIdx.x >> 6;
    int lane = threadIdx.x & 63;
    int row  = blockIdx.x * 4 + wave;
    bool isZ = row < N_VEC;
    int lr = isZ ? row : row - N_VEC;
    const float* src = isZ ? z + (size_t)row * DIM : cb + (size_t)lr * DIM;

    const float4* s4 = (const float4*)src;
    float4 v0 = s4[lane * 2];
    float4 v1 = s4[lane * 2 + 1];
    float f[8] = {v0.x, v0.y, v0.z, v0.w, v1.x, v1.y, v1.z, v1.w};

    float s = 0.0f;
    ushort8 h8;
#pragma unroll
    for (int i = 0; i < 8; ++i) { s += f[i] * f[i]; h8[i] = f2bf(f[i]); }
    ((ushort8*)(isZ ? zh : ch))[(size_t)lr * 64 + lane] = h8;

#pragma unroll
    for (int off = 32; off >= 1; off >>= 1) s += __shfl_xor(s, off, 64);
    if (lane == 0) {
        if (isZ) x2[lr] = s;
        else     hne2[lr] = -0.5f * s;
    }
}

// ---------------------------------------------------------------------------
// Kernel 2: bf16 MFMA GEMM + fused top-2 argmax of g = x.e - e2/2.
// Block = 128 rows x 4096 codes (half=blockIdx.y), 16 tiles of 256 codes.
// 4 waves in 2x2 (wM x wN); per-wave 64x128 tile = 4 M-frags x 8 N-frags.
// Partials written RACE-FREE to slot = half*2 + wN (4 slots per row).
// ---------------------------------------------------------------------------
__global__ __launch_bounds__(256, 2) void vq_gemm(
    const unsigned short* __restrict__ zh, const unsigned short* __restrict__ ch,
    const float* __restrict__ hne2,
    float* __restrict__ pG, int* __restrict__ pN, float* __restrict__ pG2) {
    __shared__ short8 AsC[1024];   // 128 rows x 8 octet-cells, XOR-swizzled (16 KB)
    __shared__ short8 BsC[2048];   // 256 codes x 8 octet-cells, XOR-swizzled (32 KB)

    const int tid  = threadIdx.x;
    const int w    = tid >> 6;
    const int lane = tid & 63;
    const int wM   = w & 1;
    const int wN   = w >> 1;
    const int rowBase   = blockIdx.x * 128;
    const int half      = blockIdx.y;
    const int codeBase0 = half * 4096;

    const int low3 = lane & 7, m15 = lane & 15, hi4 = lane >> 4;

    unsigned aOff[4];
#pragma unroll
    for (int i = 0; i < 4; ++i) {
        int cell = (w * 4 + i) * 64 + lane;
        int r = cell >> 3, qs = cell & 7, q = qs ^ (r & 7);
        aOff[i] = ((unsigned)(rowBase + r) * DIM + q * 8) * 2;
    }
    unsigned bOff[8];
#pragma unroll
    for (int i = 0; i < 8; ++i) {
        int cell = (w * 8 + i) * 64 + lane;
        int c = cell >> 3, qs = cell & 7, q = qs ^ (c & 7);
        bOff[i] = ((unsigned)c * DIM + q * 8) * 2;   // relative to code-tile base
    }

    int rIdx[4], cIdx[8];
#pragma unroll
    for (int mf = 0; mf < 4; ++mf) rIdx[mf] = (wM * 64 + mf * 16 + m15) * 8;
#pragma unroll
    for (int nf = 0; nf < 8; ++nf) cIdx[nf] = (wN * 128 + nf * 16 + m15) * 8;

    float g1[4][4], g2[4][4];
    int   n1[4][4];
#pragma unroll
    for (int mf = 0; mf < 4; ++mf)
#pragma unroll
        for (int rg = 0; rg < 4; ++rg) {
            g1[mf][rg] = -3.4e38f; g2[mf][rg] = -3.4e38f; n1[mf][rg] = 0;
        }

    const char* pA = (const char*)zh;
    for (int ct = 0; ct < 16; ++ct) {
        const int codeBase = codeBase0 + ct * 256;
        const char* pB = (const char*)ch + (size_t)codeBase * (DIM * 2);
        float4x acc[4][8];
#pragma unroll
        for (int mf = 0; mf < 4; ++mf)
#pragma unroll
            for (int nf = 0; nf < 8; ++nf) acc[mf][nf] = (float4x){0.f, 0.f, 0.f, 0.f};

        for (int dc = 0; dc < DIM; dc += 64) {
            const int dc2 = dc * 2;
            __syncthreads();
#pragma unroll
            for (int i = 0; i < 4; ++i)
                gl_lds16(pA + aOff[i] + dc2, &AsC[(w * 4 + i) * 64]);
#pragma unroll
            for (int i = 0; i < 8; ++i)
                gl_lds16(pB + bOff[i] + dc2, &BsC[(w * 8 + i) * 64]);
            __syncthreads();

#pragma unroll
            for (int ks = 0; ks < 2; ++ks) {
                const int qx = (ks * 4 + hi4) ^ low3;
                short8 a[4];
#pragma unroll
                for (int mf = 0; mf < 4; ++mf) a[mf] = AsC[rIdx[mf] + qx];
#pragma unroll
                for (int nf = 0; nf < 8; ++nf) {
                    short8 b = BsC[cIdx[nf] + qx];
#pragma unroll
                    for (int mf = 0; mf < 4; ++mf)
                        acc[mf][nf] = __builtin_amdgcn_mfma_f32_16x16x32_bf16(
                            a[mf], b, acc[mf][nf], 0, 0, 0);
                }
            }
        }

        // epilogue: running top-2 of g (ties -> g2=g1 -> gap 0 -> rescued)
#pragma unroll
        for (int nf = 0; nf < 8; ++nf) {
            int nb = codeBase + wN * 128 + nf * 16 + m15;
            float hv = hne2[nb];
#pragma unroll
            for (int mf = 0; mf < 4; ++mf) {
#pragma unroll
                for (int rg = 0; rg < 4; ++rg) {
                    float g = acc[mf][nf][rg] + hv;
                    if (g > g1[mf][rg]) {
                        g2[mf][rg] = g1[mf][rg];
                        g1[mf][rg] = g; n1[mf][rg] = nb;
                    } else {
                        g2[mf][rg] = fmaxf(g2[mf][rg], g);
                    }
                }
            }
        }
    }

    // cross-lane top-2 merge over the 16 lanes sharing each row
#pragma unroll
    for (int mf = 0; mf < 4; ++mf)
#pragma unroll
        for (int rg = 0; rg < 4; ++rg) {
            float a1 = g1[mf][rg], a2 = g2[mf][rg];
            int   an = n1[mf][rg];
#pragma unroll
            for (int off = 1; off <= 8; off <<= 1) {
                float b1 = __shfl_xor(a1, off, 64);
                int   bn = __shfl_xor(an, off, 64);
                float b2 = __shfl_xor(a2, off, 64);
                if (b1 > a1 || (b1 == a1 && bn < an)) {
                    a2 = fmaxf(a1, b2); a1 = b1; an = bn;
                } else {
                    a2 = fmaxf(a2, b1);
                }
            }
            if (m15 == 0) {
                int row  = rowBase + wM * 64 + mf * 16 + hi4 * 4 + rg;
                int slot = half * 2 + wN;          // unique per (block.y, wave-col)
                pG [slot * N_VEC + row] = a1;
                pN [slot * N_VEC + row] = an;
                pG2[slot * N_VEC + row] = a2;
            }
        }
}

// ---------------------------------------------------------------------------
// Kernel 3: merge 4 partial slots per row, flag near-ties for rescue.
// Writes merged g1 back into pG slot 0 (own row only -> safe).
// ---------------------------------------------------------------------------
__global__ __launch_bounds__(256) void vq_scan(
    float* __restrict__ pG, const int* __restrict__ pN,
    const float* __restrict__ pG2,
    int* __restrict__ provIdx, int* __restrict__ flags,
    unsigned long long* __restrict__ keys,
    int* __restrict__ rescueRows, int* __restrict__ rescueCnt) {
    int r = blockIdx.x * 256 + threadIdx.x;
    float g1 = pG[r], g2 = pG2[r];
    int   n1 = pN[r];
#pragma unroll
    for (int s = 1; s < 4; ++s) {
        float a1 = pG [s * N_VEC + r];
        int   an = pN [s * N_VEC + r];
        float a2 = pG2[s * N_VEC + r];
        if (a1 > g1 || (a1 == g1 && an < n1)) {
            g2 = fmaxf(g1, a2); g1 = a1; n1 = an;
        } else {
            g2 = fmaxf(g2, a1);
        }
    }
    provIdx[r] = n1;
    pG[r] = g1;                       // merged best (for loss)
    int fl = (g1 - g2 < MARGIN) ? 1 : 0;
    flags[r] = fl;
    if (fl) {
        keys[r] = ~0ull;
        int p = atomicAdd(rescueCnt, 1);
        rescueRows[p] = r;
    }
}

// ---------------------------------------------------------------------------
// Kernel 4: exact fp32 rescue, ROW-major over compacted flagged slots.
// Round-1 vq_main structure: 64 slots x 512 codes per block (grid.y*512),
// persistent row-tile loop over ceil(cnt/64). rescueRows is pre-zeroed so
// slots >= cnt harmlessly read row 0 (their atomics are guarded off).
// Resolution: atomicMin on packed (kv=e2/2-x.e fp32 bits | code) -> exact
// min with lowest-index tiebreak (kv > 0 for this data: e2min/2 >> x.e max).
// ---------------------------------------------------------------------------
#define RBM 64
#define RBK 256
#define RBD 32

__global__ __launch_bounds__(256, 2) void vq_rescue(
    const float* __restrict__ z, const float* __restrict__ cb,
    const float* __restrict__ hne2,
    const int* __restrict__ rescueRows, const int* __restrict__ rescueCnt,
    unsigned long long* __restrict__ keys) {
    __shared__ float As[RBD][RBM];   // 8 KB, transposed
    __shared__ float Bs[RBD][RBK];   // 32 KB, transposed
    __shared__ int   rowOf[RBM];

    const int tid = threadIdx.x;
    const int tx  = tid & 31;
    const int ty  = tid >> 5;
    const int cnt = *rescueCnt;
    const int codeBase0 = blockIdx.y * 512;      // grid.y = 16
    const int sw = (tx & 8) ? 4 : 0;
    const int sRow = tid >> 2;
    const int sQ   = tid & 3;

    for (int rt = blockIdx.x; rt * RBM < cnt; rt += gridDim.x) {
        const int slotBase = rt * RBM;
        __syncthreads();   // prior iteration fully done before rowOf/tiles change
        if (tid < RBM) rowOf[tid] = rescueRows[slotBase + tid];
        __syncthreads();

        float best[8];
        int   bidx[8];
#pragma unroll
        for (int i = 0; i < 8; ++i) { best[i] = 3.4e38f; bidx[i] = K_CODES; }

        for (int kt = 0; kt < 2; ++kt) {
            const int codeBase = codeBase0 + kt * RBK;
            float acc[8][8];
#pragma unroll
            for (int i = 0; i < 8; ++i)
#pragma unroll
                for (int j = 0; j < 8; ++j) acc[i][j] = 0.0f;

            for (int dc = 0; dc < DIM; dc += RBD) {
                __syncthreads();
                {   // stage A (indirected rows)
                    const float* srcA = z + (size_t)rowOf[sRow] * DIM + dc + sQ * 8;
                    float4 va0 = ((const float4*)srcA)[0];
                    float4 va1 = ((const float4*)srcA)[1];
                    int c0 = sQ * 8;
                    As[c0 + 0][sRow] = va0.x; As[c0 + 1][sRow] = va0.y;
                    As[c0 + 2][sRow] = va0.z; As[c0 + 3][sRow] = va0.w;
                    As[c0 + 4][sRow] = va1.x; As[c0 + 5][sRow] = va1.y;
                    As[c0 + 6][sRow] = va1.z; As[c0 + 7][sRow] = va1.w;
                }
                {   // stage B
                    const float4* srcB = (const float4*)(cb + (size_t)(codeBase + tid) * DIM + dc);
#pragma unroll
                    for (int j = 0; j < 8; ++j) {
                        float4 v = srcB[j];
                        Bs[j * 4 + 0][tid] = v.x; Bs[j * 4 + 1][tid] = v.y;
                        Bs[j * 4 + 2][tid] = v.z; Bs[j * 4 + 3][tid] = v.w;
                    }
                }
                __syncthreads();

#pragma unroll
                for (int d = 0; d < RBD; ++d) {
                    float a[8], b[8];
                    *(float4*)&a[0] = *(const float4*)&As[d][ty * 8];
                    *(float4*)&a[4] = *(const float4*)&As[d][ty * 8 + 4];
                    *(float4*)&b[0] = *(const float4*)&Bs[d][tx * 8 + sw];
                    *(float4*)&b[4] = *(const float4*)&Bs[d][tx * 8 + (sw ^ 4)];
#pragma unroll
                    for (int i = 0; i < 8; ++i)
#pragma unroll
                        for (int j = 0; j < 8; ++j) acc[i][j] += a[i] * b[j];
                }
            }

#pragma unroll
            for (int j = 0; j < 8; ++j) {
                int code = codeBase + tx * 8 + ((j < 4) ? (sw + j) : ((sw ^ 4) + j - 4));
                float ev = -hne2[code];           // = e2/2
#pragma unroll
                for (int i = 0; i < 8; ++i) {
                    float kv = ev - acc[i][j];    // = e2/2 - x.e  (> 0)
                    if (kv < best[i] || (kv == best[i] && code < bidx[i])) {
                        best[i] = kv;
                        bidx[i] = code;
                    }
                }
            }
        }

        // reduce argmin across the 32 tx-lanes sharing each row group
#pragma unroll
        for (int off = 16; off >= 1; off >>= 1) {
#pragma unroll
            for (int i = 0; i < 8; ++i) {
                float od = __shfl_xor(best[i], off, 64);
                int   oi = __shfl_xor(bidx[i], off, 64);
                if (od < best[i] || (od == best[i] && oi < bidx[i])) {
                    best[i] = od;
                    bidx[i] = oi;
                }
            }
        }

        if (tx == 0) {
#pragma unroll
            for (int i = 0; i < 8; ++i) {
                int slot = slotBase + ty * 8 + i;
                if (slot < cnt) {
                    unsigned long long key =
                        ((unsigned long long)__float_as_uint(best[i]) << 32) |
                        (unsigned long long)(unsigned)bidx[i];
                    atomicMin(&keys[rowOf[ty * 8 + i]], key);
                }
            }
        }
    }
}

// ---------------------------------------------------------------------------
// Kernel 5: final per-row results: index, counts, loss partial, z_q gather.
// ---------------------------------------------------------------------------
__global__ __launch_bounds__(256) void vq_final(
    const float* __restrict__ gBest, const int* __restrict__ provIdx,
    const int* __restrict__ flags, const unsigned long long* __restrict__ keys,
    const float* __restrict__ x2, const float* __restrict__ cb,
    float* __restrict__ zq, float* __restrict__ idxf,
    float* __restrict__ counts, float* __restrict__ lossAcc) {
    __shared__ int   sIdx[256];
    __shared__ float wsum[4];
    const int tid = threadIdx.x;
    const int r   = blockIdx.x * 256 + tid;

    int n; float dist;
    if (flags[r]) {
        unsigned long long k = keys[r];
        n = (int)(unsigned)(k & 0xffffffffu);
        float kv = __uint_as_float((unsigned)(k >> 32));
        dist = x2[r] + 2.0f * kv;          // x2 + e2 - 2 x.e
    } else {
        n = provIdx[r];
        dist = x2[r] - 2.0f * gBest[r];
    }
    sIdx[tid] = n;
    idxf[r]   = (float)n;
    atomicAdd(&counts[n], 1.0f);

    float ls = dist;
#pragma unroll
    for (int off = 32; off >= 1; off >>= 1) ls += __shfl_xor(ls, off, 64);
    if ((tid & 63) == 0) wsum[tid >> 6] = ls;
    __syncthreads();
    if (tid == 0) atomicAdd(lossAcc, wsum[0] + wsum[1] + wsum[2] + wsum[3]);

    const float4* cb4 = (const float4*)cb;
    float4* zq4 = (float4*)(zq + (size_t)blockIdx.x * 256 * DIM);
    for (int t = tid; t < 256 * (DIM / 4); t += 256) {
        int row = t >> 7, f4 = t & 127;
        zq4[(size_t)row * 128 + f4] = cb4[(size_t)sIdx[row] * 128 + f4];
    }
}

// ---------------------------------------------------------------------------
// Kernel 6: finalize scalars
// ---------------------------------------------------------------------------
__global__ __launch_bounds__(256) void vq_finalize(const float* __restrict__ counts,
                                                   const float* __restrict__ lossAcc,
                                                   float* __restrict__ out_loss,
                                                   float* __restrict__ out_perp) {
    __shared__ float wsum[4];
    int tid = threadIdx.x;
    float s = 0.0f;
    for (int i = tid; i < K_CODES; i += 256) {
        float p = counts[i] * (1.0f / (float)N_VEC);
        s += p * logf(p + 1e-10f);
    }
#pragma unroll
    for (int off = 32; off >= 1; off >>= 1) s += __shfl_xor(s, off, 64);
    if ((tid & 63) == 0) wsum[tid >> 6] = s;
    __syncthreads();
    if (tid == 0) {
        *out_perp = expf(-(wsum[0] + wsum[1] + wsum[2] + wsum[3]));
        *out_loss = 1.25f * lossAcc[0] / (float)(N_VEC * DIM);
    }
}

// ---------------------------------------------------------------------------
// ws layout (bytes), total ~44.6 MB:
//   x2 @0 131072 | hne2 @131072 32768 | counts @163840 32768 | lossAcc @196608 4
//   rescueCnt @196612 4 | provIdx @262144 131072 | flags @393216 131072
//   keys @524288 262144 | rescueRows @786432 131072
//   pG @1048576 524288 | pN @1572864 524288 | pG2 @2097152 524288
//   zh @2621440 33554432 | ch @36175872 8388608
// ---------------------------------------------------------------------------
extern "C" void kernel_launch(void* const* d_in, const int* in_sizes, int n_in,
                              void* d_out, int out_size, void* d_ws, size_t ws_size,
                              hipStream_t stream) {
    (void)in_sizes; (void)n_in; (void)out_size; (void)ws_size;
    const float* z  = (const float*)d_in[0];
    const float* cb = (const float*)d_in[1];

    char* ws = (char*)d_ws;
    float* x2        = (float*)(ws + 0);
    float* hne2      = (float*)(ws + 131072);
    float* counts    = (float*)(ws + 163840);
    float* lossAcc   = (float*)(ws + 196608);
    int*   rescueCnt = (int*)  (ws + 196612);
    int*   provIdx   = (int*)  (ws + 262144);
    int*   flags     = (int*)  (ws + 393216);
    unsigned long long* keys = (unsigned long long*)(ws + 524288);
    int*   rescueRows = (int*) (ws + 786432);
    float* pG        = (float*)(ws + 1048576);
    int*   pN        = (int*)  (ws + 1572864);
    float* pG2       = (float*)(ws + 2097152);
    unsigned short* zh = (unsigned short*)(ws + 2621440);
    unsigned short* ch = (unsigned short*)(ws + 36175872);

    float* out      = (float*)d_out;
    float* zq       = out;
    float* out_loss = out + 16777216;
    float* idxf     = out + 16777217;
    float* out_perp = out + 16777217 + 32768;

    // zero counts + lossAcc + rescueCnt (contiguous) and rescueRows
    hipMemsetAsync(counts, 0, 32768 + 8, stream);
    hipMemsetAsync(rescueRows, 0, 131072, stream);
    vq_prep<<<(N_VEC + K_CODES) / 4, 256, 0, stream>>>(z, cb, x2, hne2, zh, ch);
    dim3 grid(N_VEC / 128, 2);
    vq_gemm<<<grid, 256, 0, stream>>>(zh, ch, hne2, pG, pN, pG2);
    vq_scan<<<N_VEC / 256, 256, 0, stream>>>(pG, pN, pG2, provIdx, flags, keys,
                                             rescueRows, rescueCnt);
    dim3 rgrid(64, 16);
    vq_rescue<<<rgrid, 256, 0, stream>>>(z, cb, hne2, rescueRows, rescueCnt, keys);
    vq_final<<<N_VEC / 256, 256, 0, stream>>>(pG, provIdx, flags, keys, x2, cb,
                                              zq, idxf, counts, lossAcc);
    vq_finalize<<<1, 256, 0, stream>>>(counts, lossAcc, out_loss, out_perp);
}